// Round 2
// 919.463 us; speedup vs baseline: 1.0267x; 1.0267x over previous
//
#include <hip/hip_runtime.h>
#include <math.h>

// Problem geometry (fixed by reference: x is (256, 512, 1024) fp32)
constexpr int ROWS    = 256;
constexpr int ROWLEN  = 512 * 1024;          // elements per row
constexpr int CHUNKS  = 32;                  // blocks per row
constexpr int BLOCK   = 256;                 // threads per block (4 waves)
constexpr int ROWF4   = ROWLEN / 4;          // float4 per row (131072 = 2 MiB)
constexpr int CHUNKF4 = ROWF4 / CHUNKS;      // 4096 float4 per chunk
constexpr int F4_PER_THREAD = CHUNKF4 / BLOCK; // 16

// Native clang vector type: __builtin_nontemporal_store requires this
// (HIP_vector_type<float,4> is a struct and is rejected). Same 16B layout.
typedef float natf4 __attribute__((ext_vector_type(4)));

// Group-phased pass pairing: process 32 rows (64 MiB) at a time so that the
// quant pass re-reads data the minmax pass just staged through L2/L3.
// 64 MiB (x) << 256 MiB Infinity Cache (out is nontemporal, won't pollute).
constexpr int GROUP_ROWS = 32;
constexpr int NGROUPS    = ROWS / GROUP_ROWS; // 8

// ---------------- Kernel 1: per-(row,chunk) min/max partials ----------------
__global__ __launch_bounds__(BLOCK) void rowminmax_partial(
    const float4* __restrict__ x,
    float* __restrict__ pmin, float* __restrict__ pmax, int row0) {
  const int row   = row0 + (blockIdx.x >> 5);   // / CHUNKS
  const int chunk = blockIdx.x & (CHUNKS - 1);
  const int pidx  = row * CHUNKS + chunk;
  const float4* p = x + (size_t)row * ROWF4 + (size_t)chunk * CHUNKF4;

  float vmin = INFINITY, vmax = -INFINITY;
#pragma unroll
  for (int i = 0; i < F4_PER_THREAD; ++i) {
    float4 v = p[threadIdx.x + i * BLOCK];   // coalesced 16B/lane
    vmin = fminf(vmin, fminf(fminf(v.x, v.y), fminf(v.z, v.w)));
    vmax = fmaxf(vmax, fmaxf(fmaxf(v.x, v.y), fmaxf(v.z, v.w)));
  }

  // wave64 butterfly reduce
#pragma unroll
  for (int off = 32; off > 0; off >>= 1) {
    vmin = fminf(vmin, __shfl_xor(vmin, off, 64));
    vmax = fmaxf(vmax, __shfl_xor(vmax, off, 64));
  }

  __shared__ float smin[BLOCK / 64], smax[BLOCK / 64];
  const int wave = threadIdx.x >> 6;
  const int lane = threadIdx.x & 63;
  if (lane == 0) { smin[wave] = vmin; smax[wave] = vmax; }
  __syncthreads();
  if (threadIdx.x == 0) {
    float a = smin[0], b = smax[0];
#pragma unroll
    for (int w = 1; w < BLOCK / 64; ++w) {
      a = fminf(a, smin[w]);
      b = fmaxf(b, smax[w]);
    }
    pmin[pidx] = a;
    pmax[pidx] = b;
  }
}

// ---------------- Kernel 2: fake-quant + dequant + ReLU ----------------
__global__ __launch_bounds__(BLOCK) void quant_relu(
    const float4* __restrict__ x, float4* __restrict__ out,
    const float* __restrict__ pmin, const float* __restrict__ pmax, int row0) {
  const int row   = row0 + (blockIdx.x >> 5);
  const int chunk = blockIdx.x & (CHUNKS - 1);

  // Fold this row's 32 partials (uniform addresses -> scalar loads, L2-hot).
  float m = INFINITY, M = -INFINITY;
#pragma unroll
  for (int i = 0; i < CHUNKS; ++i) {
    m = fminf(m, pmin[row * CHUNKS + i]);
    M = fmaxf(M, pmax[row * CHUNKS + i]);
  }
  const float rng   = M - m;
  const float scale = 254.0f / rng;   // quant scale
  const float step  = rng / 254.0f;   // dequant step

  const float4* p = x   + (size_t)row * ROWF4 + (size_t)chunk * CHUNKF4;
  float4*       q = out + (size_t)row * ROWF4 + (size_t)chunk * CHUNKF4;

#pragma unroll 4
  for (int i = 0; i < F4_PER_THREAD; ++i) {
    float4 v = p[threadIdx.x + i * BLOCK];   // L2/L3-hot: staged by pass 1 of this group
    natf4 o;
    // r = round_half_even(254*(x-m)/rng - 127); out = relu((r+127)*rng/254 + m)
    o.x = fmaxf(fmaf(rintf(fmaf(v.x - m, scale, -127.0f)) + 127.0f, step, m), 0.0f);
    o.y = fmaxf(fmaf(rintf(fmaf(v.y - m, scale, -127.0f)) + 127.0f, step, m), 0.0f);
    o.z = fmaxf(fmaf(rintf(fmaf(v.z - m, scale, -127.0f)) + 127.0f, step, m), 0.0f);
    o.w = fmaxf(fmaf(rintf(fmaf(v.w - m, scale, -127.0f)) + 127.0f, step, m), 0.0f);
    // Nontemporal: pure streaming output, don't let it evict this group's x
    // from L2/L3 (pass-2 reuse of x depends on cache residency).
    __builtin_nontemporal_store(o, (natf4*)&q[threadIdx.x + i * BLOCK]);
  }
}

extern "C" void kernel_launch(void* const* d_in, const int* in_sizes, int n_in,
                              void* d_out, int out_size, void* d_ws, size_t ws_size,
                              hipStream_t stream) {
  const float4* x   = (const float4*)d_in[0];
  float4*       out = (float4*)d_out;
  float*        pmin = (float*)d_ws;                 // ROWS*CHUNKS floats
  float*        pmax = pmin + ROWS * CHUNKS;         // ROWS*CHUNKS floats (64 KiB total)

  // Paired group launches: minmax(g) stages 64 MiB through L2/L3, quant(g)
  // immediately re-reads it from cache instead of HBM.
  for (int g = 0; g < NGROUPS; ++g) {
    const int row0 = g * GROUP_ROWS;
    rowminmax_partial<<<GROUP_ROWS * CHUNKS, BLOCK, 0, stream>>>(x, pmin, pmax, row0);
    quant_relu<<<GROUP_ROWS * CHUNKS, BLOCK, 0, stream>>>(x, out, pmin, pmax, row0);
  }
}